// Round 1
// baseline (245.691 us; speedup 1.0000x reference)
//
#include <hip/hip_runtime.h>

#define BTOT 32768
#define FDIM 128
#define TDIM 32
#define DDIM 16
#define HDIM 10
#define ALPHA_C 0.1f
#define MARGIN_C 1.0f
#define SLOPE_C 0.2f
#define OFFSET_C 1.0e6f

// ws float offsets
#define WS_A0 0            // 32*128*10 = 40960 floats
#define WS_MEAN 40960      // 320 floats
#define WS_TC 41280        // 1 float (+pad to 41344)
#define WS_CE 41344        // 32768 floats

__device__ __forceinline__ float leaky(float x) { return x >= 0.f ? x : SLOPE_C * x; }

// A0[t,n,o] = sum_d aw[t,n,d] * W0[o,d]
__global__ void prep_kernel(const float* __restrict__ aw, const float* __restrict__ W0,
                            float* __restrict__ A0) {
    int idx = blockIdx.x * blockDim.x + threadIdx.x;   // t*F + n, 4096 total
    if (idx >= TDIM * FDIM) return;
    const float* a = aw + (size_t)idx * DDIM;
    float* dst = A0 + (size_t)idx * HDIM;
#pragma unroll
    for (int o = 0; o < HDIM; ++o) {
        float s = 0.f;
#pragma unroll
        for (int d = 0; d < DDIM; ++d) s += a[d] * W0[o * DDIM + d];
        dst[o] = s;
    }
}

// One block: 128 b's x 2 t-halves. Computes rep chain, writes batch_rep, mean CE per b.
__global__ __launch_bounds__(256) void phase1_kernel(
    const float* __restrict__ X, const float* __restrict__ A0,
    const float* __restrict__ W1, const float* __restrict__ W2,
    const float* __restrict__ W3, const float* __restrict__ Wh,
    const float* __restrict__ bh,
    float* __restrict__ out_rep, float* __restrict__ ce_mean)
{
    __shared__ float xs[128][129];   // +1 pad -> 2-way bank conflict (free)
    __shared__ float ce_part[256];
    int tid = threadIdx.x;
    int b0 = blockIdx.x * 128;

    // coalesced X stage: 128 rows x 128 cols
    for (int i = tid; i < 128 * FDIM / 4; i += 256) {
        float4 v = reinterpret_cast<const float4*>(X + (size_t)b0 * FDIM)[i];
        int row = i >> 5;
        int col = (i & 31) * 4;
        xs[row][col + 0] = v.x; xs[row][col + 1] = v.y;
        xs[row][col + 2] = v.z; xs[row][col + 3] = v.w;
    }
    __syncthreads();

    int b_local = tid & 127;
    // wave-uniform half index -> uniform t -> scalar loads for A0/weights
    int half = __builtin_amdgcn_readfirstlane(tid >> 7);
    float ce_sum = 0.f;

    for (int tt = 0; tt < 16; ++tt) {
        int t = half * 16 + tt;
        const float* a0 = A0 + (size_t)t * FDIM * HDIM;
        float h[HDIM];
#pragma unroll
        for (int o = 0; o < HDIM; ++o) h[o] = 0.f;
        for (int n = 0; n < FDIM; ++n) {
            float xv = xs[b_local][n];
            const float* ar = a0 + n * HDIM;
#pragma unroll
            for (int o = 0; o < HDIM; ++o) h[o] += xv * ar[o];
        }
        float g[HDIM], lh[HDIM];
#pragma unroll
        for (int o = 0; o < HDIM; ++o) lh[o] = leaky(h[o]);
#pragma unroll
        for (int o = 0; o < HDIM; ++o) { float s = 0.f;
#pragma unroll
            for (int j = 0; j < HDIM; ++j) s += W1[o * HDIM + j] * lh[j]; g[o] = s; }
#pragma unroll
        for (int o = 0; o < HDIM; ++o) lh[o] = leaky(g[o]);
#pragma unroll
        for (int o = 0; o < HDIM; ++o) { float s = 0.f;
#pragma unroll
            for (int j = 0; j < HDIM; ++j) s += W2[o * HDIM + j] * lh[j]; h[o] = s; }
#pragma unroll
        for (int o = 0; o < HDIM; ++o) lh[o] = leaky(h[o]);
#pragma unroll
        for (int o = 0; o < HDIM; ++o) { float s = 0.f;
#pragma unroll
            for (int j = 0; j < HDIM; ++j) s += W3[o * HDIM + j] * lh[j]; g[o] = s; }

        // g = rep[:,t]; batch_rep[b][t][o]
        float* orp = out_rep + ((size_t)(b0 + b_local) * TDIM + t) * HDIM;
#pragma unroll
        for (int o = 0; o < HDIM; ++o) orp[o] = g[o];

        // head: pred[o] = Wh[o,:]*leaky(rep) + bh; CE with class t over 32 classes
#pragma unroll
        for (int o = 0; o < HDIM; ++o) lh[o] = leaky(g[o]);
        float p[TDIM];
        float mx = -1e30f;
#pragma unroll
        for (int o = 0; o < TDIM; ++o) {
            float s = bh[o];
#pragma unroll
            for (int j = 0; j < HDIM; ++j) s += Wh[o * HDIM + j] * lh[j];
            p[o] = s; mx = fmaxf(mx, s);
        }
        float se = 0.f, pt = 0.f;
#pragma unroll
        for (int o = 0; o < TDIM; ++o) { se += __expf(p[o] - mx); if (o == t) pt = p[o]; }
        float lse = mx + __logf(se);
        ce_sum += (lse - pt);
    }
    ce_part[tid] = ce_sum;
    __syncthreads();
    if (tid < 128)
        ce_mean[b0 + tid] = (ce_part[tid] + ce_part[tid + 128]) * (1.f / TDIM);
}

// mean accumulation: block = 320 threads (one per (t,h)), 128 b's per block, coalesced
__global__ void meanred_kernel(const float* __restrict__ rep, float* __restrict__ mean_acc)
{
    int j = threadIdx.x;                   // 0..319
    const float* base = rep + (size_t)blockIdx.x * 128 * (TDIM * HDIM);
    float s0 = 0, s1 = 0, s2 = 0, s3 = 0;
    for (int b = 0; b < 128; b += 4) {
        s0 += base[(size_t)(b + 0) * 320 + j];
        s1 += base[(size_t)(b + 1) * 320 + j];
        s2 += base[(size_t)(b + 2) * 320 + j];
        s3 += base[(size_t)(b + 3) * 320 + j];
    }
    atomicAdd(&mean_acc[j], s0 + s1 + s2 + s3);
}

// triplet-center hinge: 1 thread per (b,t)
__global__ __launch_bounds__(256) void tc_kernel(const float* __restrict__ rep,
    const float* __restrict__ mean_acc, float* __restrict__ tc_sum)
{
    __shared__ float mm[TDIM * HDIM];
    __shared__ float wpart[4];
    int tid = threadIdx.x;
    for (int i = tid; i < TDIM * HDIM; i += 256) mm[i] = mean_acc[i] * (1.f / BTOT);
    __syncthreads();
    size_t idx = (size_t)blockIdx.x * 256 + tid;   // b*32 + t
    int t = (int)(idx & 31);
    const float* r = rep + idx * HDIM;
    float rv[HDIM];
#pragma unroll
    for (int h = 0; h < HDIM; ++h) rv[h] = r[h];
    float pos = 0.f, neg = 1e30f;
#pragma unroll
    for (int c = 0; c < TDIM; ++c) {
        float s = 0.f;
#pragma unroll
        for (int h = 0; h < HDIM; ++h) { float d = rv[h] - mm[c * HDIM + h]; s += d * d; }
        if (c == t) pos = s;
        float s2 = (c == t) ? s + OFFSET_C : s;
        neg = fminf(neg, s2);
    }
    float hinge = fmaxf(pos + MARGIN_C - neg, 0.f);
#pragma unroll
    for (int m = 32; m; m >>= 1) hinge += __shfl_xor(hinge, m, 64);
    int lane = tid & 63, wid = tid >> 6;
    if (lane == 0) wpart[wid] = hinge;
    __syncthreads();
    if (tid == 0) atomicAdd(tc_sum, wpart[0] + wpart[1] + wpart[2] + wpart[3]);
}

__global__ void final_kernel(const float* __restrict__ ce_mean,
                             const float* __restrict__ tc_sum, float* __restrict__ loss)
{
    int b = blockIdx.x * blockDim.x + threadIdx.x;
    if (b < BTOT)
        loss[b] = ALPHA_C * (tc_sum[0] * (1.f / ((float)BTOT * TDIM))) + ce_mean[b];
}

extern "C" void kernel_launch(void* const* d_in, const int* in_sizes, int n_in,
                              void* d_out, int out_size, void* d_ws, size_t ws_size,
                              hipStream_t stream) {
    const float* X  = (const float*)d_in[0];
    const float* aw = (const float*)d_in[1];
    const float* W0 = (const float*)d_in[2];
    const float* W1 = (const float*)d_in[3];
    const float* W2 = (const float*)d_in[4];
    const float* W3 = (const float*)d_in[5];
    const float* Wh = (const float*)d_in[6];
    const float* bh = (const float*)d_in[7];
    float* ws = (float*)d_ws;
    float* A0       = ws + WS_A0;
    float* mean_acc = ws + WS_MEAN;
    float* tc_sum   = ws + WS_TC;
    float* ce_mean  = ws + WS_CE;
    float* out_rep = (float*)d_out;
    float* loss = out_rep + (size_t)BTOT * TDIM * HDIM;

    // zero mean_acc + tc_sum (384 floats); capture-safe async memset
    hipMemsetAsync(mean_acc, 0, 384 * sizeof(float), stream);
    prep_kernel<<<16, 256, 0, stream>>>(aw, W0, A0);
    phase1_kernel<<<256, 256, 0, stream>>>(X, A0, W1, W2, W3, Wh, bh, out_rep, ce_mean);
    meanred_kernel<<<256, 320, 0, stream>>>(out_rep, mean_acc);
    tc_kernel<<<(BTOT * TDIM) / 256, 256, 0, stream>>>(out_rep, mean_acc, tc_sum);
    final_kernel<<<BTOT / 256, 256, 0, stream>>>(ce_mean, tc_sum, loss);
}